// Round 17
// baseline (154.723 us; speedup 1.0000x reference)
//
#include <hip/hip_runtime.h>

typedef _Float16 h2 __attribute__((ext_vector_type(2)));
typedef _Float16 h8 __attribute__((ext_vector_type(8)));

#define WSTRIDE 108   // dwords per position in weight LDS (27 taps x 4 dwords)

// ---- DPP wave-64 sum (VALU pipe): full sum lands in lane 63 ----
template <int CTRL>
__device__ __forceinline__ float dpp_stage(float v) {
    int x = __builtin_amdgcn_update_dpp(0, __float_as_int(v), CTRL, 0xf, 0xf, true);
    return v + __int_as_float(x);
}
__device__ __forceinline__ float wave_sum(float v) {
    v = dpp_stage<0x111>(v);  // row_shr:1
    v = dpp_stage<0x112>(v);  // row_shr:2
    v = dpp_stage<0x114>(v);  // row_shr:4
    v = dpp_stage<0x118>(v);  // row_shr:8
    v = dpp_stage<0x142>(v);  // row_bcast:15
    v = dpp_stage<0x143>(v);  // row_bcast:31
    return v;
}
__device__ __forceinline__ float bcast63(float v) {
    return __int_as_float(__builtin_amdgcn_readlane(__float_as_int(v), 63));
}
__device__ __forceinline__ h2 mid2(h2 lo, h2 hi) {
    int r = __builtin_amdgcn_alignbit(__builtin_bit_cast(int, hi),
                                      __builtin_bit_cast(int, lo), 16);
    return __builtin_bit_cast(h2, r);
}
__device__ __forceinline__ h2 pkrtz(float a, float b) {
    return __builtin_bit_cast(h2, __builtin_amdgcn_cvt_pkrtz(a, b));
}

// Compiler-level memory fence (emits nothing): pins LDS op program order for
// the single-wave read/write discipline on the private data buffers (round-1
// stale-neighbor bug; validated PASS r2/r3/r10/r12-r16).
#define MEMFENCE() asm volatile("" ::: "memory")

// h2 slice k (elements 2k,2k+1) of an h8 — register-select, no instructions
#define SL(W, K) __builtin_shufflevector(W, W, 2*(K), 2*(K)+1)

// one window column, taps T..T+2, TWO batches: 3 ds_read_b128 weight reads
// feed BOTH batches (weight-LDS traffic per output halves vs r16), 10 data
// dword reads, 8 alignbit, 72 v_pk_fma_f16 -> 16 outputs. The A and B FMA
// chains are independent -> they interleave and hide each other's latency
// (r5-proven pairing mechanism, now without the weight-register cost).
#define COLT2(O, T) {                                                          \
    h8 WA = wp8[(T)];                                                          \
    h8 WB = wp8[(T) + 1];                                                      \
    h8 WC = wp8[(T) + 2];                                                      \
    h2 A0 = bpA[(O) + 0], A1 = bpA[(O) + 1], A2 = bpA[(O) + 2],                \
       A3 = bpA[(O) + 3], A4 = bpA[(O) + 4];                                   \
    h2 MA0 = mid2(A0, A1), MA1 = mid2(A1, A2), MA2 = mid2(A2, A3),             \
       MA3 = mid2(A3, A4);                                                     \
    h2 B0 = bpB[(O) + 0], B1 = bpB[(O) + 1], B2 = bpB[(O) + 2],                \
       B3 = bpB[(O) + 3], B4 = bpB[(O) + 4];                                   \
    h2 MB0 = mid2(B0, B1), MB1 = mid2(B1, B2), MB2 = mid2(B2, B3),             \
       MB3 = mid2(B3, B4);                                                     \
    ddA0 = __builtin_elementwise_fma(A0, SL(WA, 0), ddA0);                     \
    ddA1 = __builtin_elementwise_fma(A1, SL(WA, 1), ddA1);                     \
    ddA2 = __builtin_elementwise_fma(A2, SL(WA, 2), ddA2);                     \
    ddA3 = __builtin_elementwise_fma(A3, SL(WA, 3), ddA3);                     \
    ddB0 = __builtin_elementwise_fma(B0, SL(WA, 0), ddB0);                     \
    ddB1 = __builtin_elementwise_fma(B1, SL(WA, 1), ddB1);                     \
    ddB2 = __builtin_elementwise_fma(B2, SL(WA, 2), ddB2);                     \
    ddB3 = __builtin_elementwise_fma(B3, SL(WA, 3), ddB3);                     \
    ddA0 = __builtin_elementwise_fma(MA0, SL(WB, 0), ddA0);                    \
    ddA1 = __builtin_elementwise_fma(MA1, SL(WB, 1), ddA1);                    \
    ddA2 = __builtin_elementwise_fma(MA2, SL(WB, 2), ddA2);                    \
    ddA3 = __builtin_elementwise_fma(MA3, SL(WB, 3), ddA3);                    \
    ddB0 = __builtin_elementwise_fma(MB0, SL(WB, 0), ddB0);                    \
    ddB1 = __builtin_elementwise_fma(MB1, SL(WB, 1), ddB1);                    \
    ddB2 = __builtin_elementwise_fma(MB2, SL(WB, 2), ddB2);                    \
    ddB3 = __builtin_elementwise_fma(MB3, SL(WB, 3), ddB3);                    \
    ddA0 = __builtin_elementwise_fma(A1, SL(WC, 0), ddA0);                     \
    ddA1 = __builtin_elementwise_fma(A2, SL(WC, 1), ddA1);                     \
    ddA2 = __builtin_elementwise_fma(A3, SL(WC, 2), ddA2);                     \
    ddA3 = __builtin_elementwise_fma(A4, SL(WC, 3), ddA3);                     \
    ddB0 = __builtin_elementwise_fma(B1, SL(WC, 0), ddB0);                     \
    ddB1 = __builtin_elementwise_fma(B2, SL(WC, 1), ddB1);                     \
    ddB2 = __builtin_elementwise_fma(B3, SL(WC, 2), ddB2);                     \
    ddB3 = __builtin_elementwise_fma(B4, SL(WC, 3), ddB3); }

// normalized-dot correction + bias + silu + residual for one output
#define OUTK(CK, DDF, SWK, BK, RK, NM, IS) {                                   \
    float u = fmaf(fmaf(SWK, NM, DDF), IS, BK);                                \
    CK += RK * (u * __builtin_amdgcn_rcpf(1.f + __expf(-u))); }

// 4 waves x 2 batches = 8 batches of ONE tile per wg (same LDS/W-amortization
// as r16), but each wave now carries TWO independent dot/epilogue/DPP chains:
// 2x issue per resident wave at the SAME residency (r16 diagnosis: latency-
// bound at 3.5 waves/SIMD, VALUBusy==44%≈residency-limited issue).
__global__ __launch_bounds__(256, 1)
void gridnet_kernel(const float* __restrict__ W,
                    const float* __restrict__ Bias,
                    const float* __restrict__ Rs,
                    const float* __restrict__ X,
                    float* __restrict__ Y,
                    int n_batch)
{
    __shared__ __align__(16) int wlds[64 * WSTRIDE];    // 27.6 KB, shared
    __shared__ __align__(16) h2 dbuf[8][500];           // 8 x 2 KB, per-batch

    const int tid  = threadIdx.x;      // 256 threads = 4 waves
    const int wave = tid >> 6;
    const int lane = tid & 63;
    const int lx   = lane >> 3;        // 0..7
    const int ly   = lane & 7;

    // wg = one tile x 8 batches; wave = 2 batches (2*wave, 2*wave+1)
    const int no    = n_batch >> 3;             // batch octets per tile (2)
    const int bid   = (int)blockIdx.x;
    const int r     = bid / no;                 // spatial block 0..511
    const int ob    = bid - r * no;
    const int batchA = 8 * ob + 2 * wave;       // and batchA+1
    const int gm0 = (r >> 6) << 3;
    const int gn0 = ((r >> 3) & 7) << 3;
    const int gk0 = (r & 7) << 3;

    const float* xb = X + ((size_t)batchA << 18);
    h2* const myA = dbuf[2 * wave];
    h2* const myB = dbuf[2 * wave + 1];

    // -------- data staging: both batches per wave; stats on rounded ---------
    float sA_all = 0.f, qA_all = 0.f, sA_int = 0.f, qA_int = 0.f;
    float sB_all = 0.f, qB_all = 0.f, sB_int = 0.f, qB_int = 0.f;
    #pragma unroll 1
    for (int c = lane; c < 100; c += 64) {
        int x = c / 10, y = c - (c / 10) * 10;   // padded coords 0..9
        int m = gm0 + x - 1, n = gn0 + y - 1;
        bool row_ok = ((unsigned)m < 64u) & ((unsigned)n < 64u);
        float4 fa = {0.f, 0.f, 0.f, 0.f}, fb = {0.f, 0.f, 0.f, 0.f};
        float4 ga = {0.f, 0.f, 0.f, 0.f}, gb = {0.f, 0.f, 0.f, 0.f};
        float vz0A = 0.f, vz9A = 0.f, vz0B = 0.f, vz9B = 0.f;
        if (row_ok) {
            const float* rp = xb + (m * 4096 + n * 64);
            const float* rq = rp + (1 << 18);             // next batch
            fa = *(const float4*)(rp + gk0);
            fb = *(const float4*)(rp + gk0 + 4);
            ga = *(const float4*)(rq + gk0);
            gb = *(const float4*)(rq + gk0 + 4);
            if (gk0 > 0)  { vz0A = rp[gk0 - 1]; vz0B = rq[gk0 - 1]; }
            if (gk0 < 56) { vz9A = rp[gk0 + 8]; vz9B = rq[gk0 + 8]; }
        }
        h2 a0 = pkrtz(vz0A, fa.x), a1 = pkrtz(fa.y, fa.z), a2 = pkrtz(fa.w, fb.x),
           a3 = pkrtz(fb.y, fb.z), a4 = pkrtz(fb.w, vz9A);
        h2 b0 = pkrtz(vz0B, ga.x), b1 = pkrtz(ga.y, ga.z), b2 = pkrtz(ga.w, gb.x),
           b3 = pkrtz(gb.y, gb.z), b4 = pkrtz(gb.w, vz9B);
        myA[c * 5 + 0] = a0; myA[c * 5 + 1] = a1; myA[c * 5 + 2] = a2;
        myA[c * 5 + 3] = a3; myA[c * 5 + 4] = a4;
        myB[c * 5 + 0] = b0; myB[c * 5 + 1] = b1; myB[c * 5 + 2] = b2;
        myB[c * 5 + 3] = b3; myB[c * 5 + 4] = b4;
        float tA0=(float)a0.x, tA1=(float)a0.y, tA2=(float)a1.x, tA3=(float)a1.y,
              tA4=(float)a2.x, tA5=(float)a2.y, tA6=(float)a3.x, tA7=(float)a3.y,
              tA8=(float)a4.x, tA9=(float)a4.y;
        float tB0=(float)b0.x, tB1=(float)b0.y, tB2=(float)b1.x, tB3=(float)b1.y,
              tB4=(float)b2.x, tB5=(float)b2.y, tB6=(float)b3.x, tB7=(float)b3.y,
              tB8=(float)b4.x, tB9=(float)b4.y;
        float sA8 = tA1+tA2+tA3+tA4+tA5+tA6+tA7+tA8;
        float qA8 = tA1*tA1+tA2*tA2+tA3*tA3+tA4*tA4+tA5*tA5+tA6*tA6+tA7*tA7+tA8*tA8;
        float sB8 = tB1+tB2+tB3+tB4+tB5+tB6+tB7+tB8;
        float qB8 = tB1*tB1+tB2*tB2+tB3*tB3+tB4*tB4+tB5*tB5+tB6*tB6+tB7*tB7+tB8*tB8;
        sA_all += sA8 + tA0 + tA9;
        qA_all += qA8 + tA0*tA0 + tA9*tA9;
        sB_all += sB8 + tB0 + tB9;
        qB_all += qB8 + tB0*tB0 + tB9*tB9;
        bool inter = ((unsigned)(x - 1) < 8u) & ((unsigned)(y - 1) < 8u);
        if (inter) { sA_int += sA8; qA_int += qA8;
                     sB_int += sB8; qB_int += qB8; }
    }

    // -------- cooperative weight staging: 27 taps x 64 positions, once ------
    #pragma unroll 1
    for (int j = tid; j < 1728; j += 256) {
        int tap = j >> 6;                   // 0..26
        int pos = j & 63;
        int plx = pos >> 3, ply = pos & 7;
        const float* wp = W + ((size_t)tap << 18)
                        + (((size_t)(gm0 + plx)) << 12) + ((gn0 + ply) << 6) + gk0;
        float4 fa = *(const float4*)(wp);
        float4 fb = *(const float4*)(wp + 4);
        int4 v = { __builtin_bit_cast(int, pkrtz(fa.x, fa.y)),
                   __builtin_bit_cast(int, pkrtz(fa.z, fa.w)),
                   __builtin_bit_cast(int, pkrtz(fb.x, fb.y)),
                   __builtin_bit_cast(int, pkrtz(fb.z, fb.w)) };
        *(int4*)&wlds[pos * WSTRIDE + tap * 4] = v;     // aligned ds_write_b128
    }

    // -------- per-wave block stats (both batches): DPP + readlane only ------
    float SA_all = bcast63(wave_sum(sA_all));
    float QA_all = bcast63(wave_sum(qA_all));
    float SiA    = bcast63(wave_sum(sA_int));
    float QiA    = bcast63(wave_sum(qA_int));
    float SB_all = bcast63(wave_sum(sB_all));
    float QB_all = bcast63(wave_sum(qB_all));
    float SiB    = bcast63(wave_sum(sB_int));
    float QiB    = bcast63(wave_sum(qB_int));
    const float halo_sA = SA_all - SiA, halo_qA = QA_all - QiA;
    const float halo_sB = SB_all - SiB, halo_qB = QB_all - QiB;

    __syncthreads();   // the ONLY barrier: weights visible to all 4 waves

    // -------- per-thread loop-invariant state -------------------------------
    const h8* const wp8 = (const h8*)&wlds[lane * WSTRIDE];
    h2* const bpA = &myA[5 * (lx * 10 + ly)];   // window corner; own col = +55
    h2* const bpB = &myB[5 * (lx * 10 + ly)];

    // sw sums over the ROUNDED weights (shared by both batches)
    float sw0=0.f, sw1=0.f, sw2=0.f, sw3=0.f, sw4=0.f, sw5=0.f, sw6=0.f, sw7=0.f;
    #pragma unroll
    for (int t = 0; t < 27; ++t) {
        h8 w = wp8[t];
        sw0 += (float)w[0]; sw1 += (float)w[1]; sw2 += (float)w[2];
        sw3 += (float)w[3]; sw4 += (float)w[4]; sw5 += (float)w[5];
        sw6 += (float)w[6]; sw7 += (float)w[7];
    }

    const size_t ofs = (((size_t)(gm0 + lx)) << 12) + ((gn0 + ly) << 6) + gk0;
    float4 ba = *(const float4*)(Bias + ofs), bb = *(const float4*)(Bias + ofs + 4);
    float4 ra = *(const float4*)(Rs + ofs),   rb = *(const float4*)(Rs + ofs + 4);

    // own column initial state (rounded values from LDS), both batches
    h2 eA0 = bpA[55], eA1 = bpA[56], eA2 = bpA[57], eA3 = bpA[58], eA4 = bpA[59];
    h2 eB0 = bpB[55], eB1 = bpB[56], eB2 = bpB[57], eB3 = bpB[58], eB4 = bpB[59];
    float z0A = (float)eA0.x, z9A = (float)eA4.y;
    float z0B = (float)eB0.x, z9B = (float)eB4.y;
    float cA1=(float)eA0.y, cA2=(float)eA1.x, cA3=(float)eA1.y, cA4=(float)eA2.x,
          cA5=(float)eA2.y, cA6=(float)eA3.x, cA7=(float)eA3.y, cA8=(float)eA4.x;
    float cB1=(float)eB0.y, cB2=(float)eB1.x, cB3=(float)eB1.y, cB4=(float)eB2.x,
          cB5=(float)eB2.y, cB6=(float)eB3.x, cB7=(float)eB3.y, cB8=(float)eB4.x;

    const float inv_n = 1.0f / 1000.0f;

    // 8 iterations, ZERO barriers (single-wave discipline + fences)
    #pragma unroll 1
    for (int it = 0; it < 8; ++it) {
        float meanA  = (halo_sA + SiA) * inv_n;
        float istdA  = rsqrtf((halo_qA + QiA) * inv_n - meanA * meanA + 1e-5f);
        float nmeanA = -meanA;
        float meanB  = (halo_sB + SiB) * inv_n;
        float istdB  = rsqrtf((halo_qB + QiB) * inv_n - meanB * meanB + 1e-5f);
        float nmeanB = -meanB;

        h2 ddA0 = { (_Float16)0.f, (_Float16)0.f };
        h2 ddA1 = ddA0, ddA2 = ddA0, ddA3 = ddA0;
        h2 ddB0 = ddA0, ddB1 = ddA0, ddB2 = ddA0, ddB3 = ddA0;
        COLT2(0,    0)
        COLT2(5,    3)
        COLT2(10,   6)
        COLT2(50,   9)
        COLT2(55,  12)
        COLT2(60,  15)
        COLT2(100, 18)
        COLT2(105, 21)
        COLT2(110, 24)

        MEMFENCE();  // all column reads issue before the stores below

        OUTK(cA1, (float)ddA0.x, sw0, ba.x, ra.x, nmeanA, istdA)
        OUTK(cA2, (float)ddA0.y, sw1, ba.y, ra.y, nmeanA, istdA)
        OUTK(cA3, (float)ddA1.x, sw2, ba.z, ra.z, nmeanA, istdA)
        OUTK(cA4, (float)ddA1.y, sw3, ba.w, ra.w, nmeanA, istdA)
        OUTK(cA5, (float)ddA2.x, sw4, bb.x, rb.x, nmeanA, istdA)
        OUTK(cA6, (float)ddA2.y, sw5, bb.y, rb.y, nmeanA, istdA)
        OUTK(cA7, (float)ddA3.x, sw6, bb.z, rb.z, nmeanA, istdA)
        OUTK(cA8, (float)ddA3.y, sw7, bb.w, rb.w, nmeanA, istdA)
        OUTK(cB1, (float)ddB0.x, sw0, ba.x, ra.x, nmeanB, istdB)
        OUTK(cB2, (float)ddB0.y, sw1, ba.y, ra.y, nmeanB, istdB)
        OUTK(cB3, (float)ddB1.x, sw2, ba.z, ra.z, nmeanB, istdB)
        OUTK(cB4, (float)ddB1.y, sw3, ba.w, ra.w, nmeanB, istdB)
        OUTK(cB5, (float)ddB2.x, sw4, bb.x, rb.x, nmeanB, istdB)
        OUTK(cB6, (float)ddB2.y, sw5, bb.y, rb.y, nmeanB, istdB)
        OUTK(cB7, (float)ddB3.x, sw6, bb.z, rb.z, nmeanB, istdB)
        OUTK(cB8, (float)ddB3.y, sw7, bb.w, rb.w, nmeanB, istdB)

        if (it != 7) {   // last iteration: no writeback, no stats
            eA0 = pkrtz(z0A, cA1); eA1 = pkrtz(cA2, cA3); eA2 = pkrtz(cA4, cA5);
            eA3 = pkrtz(cA6, cA7); eA4 = pkrtz(cA8, z9A);
            bpA[55] = eA0; bpA[56] = eA1; bpA[57] = eA2; bpA[58] = eA3; bpA[59] = eA4;
            eB0 = pkrtz(z0B, cB1); eB1 = pkrtz(cB2, cB3); eB2 = pkrtz(cB4, cB5);
            eB3 = pkrtz(cB6, cB7); eB4 = pkrtz(cB8, z9B);
            bpB[55] = eB0; bpB[56] = eB1; bpB[57] = eB2; bpB[58] = eB3; bpB[59] = eB4;

            MEMFENCE();  // stores stay above next iteration's reads

            float spA = ((cA1 + cA2) + (cA3 + cA4)) + ((cA5 + cA6) + (cA7 + cA8));
            float qpA = ((cA1*cA1 + cA2*cA2) + (cA3*cA3 + cA4*cA4)) +
                        ((cA5*cA5 + cA6*cA6) + (cA7*cA7 + cA8*cA8));
            float spB = ((cB1 + cB2) + (cB3 + cB4)) + ((cB5 + cB6) + (cB7 + cB8));
            float qpB = ((cB1*cB1 + cB2*cB2) + (cB3*cB3 + cB4*cB4)) +
                        ((cB5*cB5 + cB6*cB6) + (cB7*cB7 + cB8*cB8));
            SiA = bcast63(wave_sum(spA));
            QiA = bcast63(wave_sum(qpA));
            SiB = bcast63(wave_sum(spB));
            QiB = bcast63(wave_sum(qpB));
        }
    }

    float* yp = Y + ((size_t)batchA << 18) + ofs;
    *(float4*)(yp)     = make_float4(cA1, cA2, cA3, cA4);
    *(float4*)(yp + 4) = make_float4(cA5, cA6, cA7, cA8);
    float* yq = yp + (1 << 18);
    *(float4*)(yq)     = make_float4(cB1, cB2, cB3, cB4);
    *(float4*)(yq + 4) = make_float4(cB5, cB6, cB7, cB8);
}

extern "C" void kernel_launch(void* const* d_in, const int* in_sizes, int n_in,
                              void* d_out, int out_size, void* d_ws, size_t ws_size,
                              hipStream_t stream) {
    const float* W = (const float*)d_in[0];   // (27,64,64,64)
    const float* B = (const float*)d_in[1];   // (64,64,64)
    const float* R = (const float*)d_in[2];   // (64,64,64)
    const float* X = (const float*)d_in[3];   // (16,64,64,64)
    float* Y = (float*)d_out;

    int n_batch = in_sizes[3] >> 18;          // 64^3 per sample (16, div by 8)
    dim3 grid(512 * (n_batch >> 3)), block(256);
    hipLaunchKernelGGL(gridnet_kernel, grid, block, 0, stream, W, B, R, X, Y, n_batch);
}

// Round 18
// 145.322 us; speedup vs baseline: 1.0647x; 1.0647x over previous
//
#include <hip/hip_runtime.h>

typedef _Float16 h2 __attribute__((ext_vector_type(2)));
typedef _Float16 h8 __attribute__((ext_vector_type(8)));

#define WSTRIDE 108   // dwords per position in weight LDS (27 taps x 4 dwords)

// ---- DPP wave-64 sum (VALU pipe): full sum lands in lane 63 ----
template <int CTRL>
__device__ __forceinline__ float dpp_stage(float v) {
    int x = __builtin_amdgcn_update_dpp(0, __float_as_int(v), CTRL, 0xf, 0xf, true);
    return v + __int_as_float(x);
}
__device__ __forceinline__ float wave_sum(float v) {
    v = dpp_stage<0x111>(v);  // row_shr:1
    v = dpp_stage<0x112>(v);  // row_shr:2
    v = dpp_stage<0x114>(v);  // row_shr:4
    v = dpp_stage<0x118>(v);  // row_shr:8
    v = dpp_stage<0x142>(v);  // row_bcast:15
    v = dpp_stage<0x143>(v);  // row_bcast:31
    return v;
}
__device__ __forceinline__ float bcast63(float v) {
    return __int_as_float(__builtin_amdgcn_readlane(__float_as_int(v), 63));
}
__device__ __forceinline__ h2 mid2(h2 lo, h2 hi) {
    int r = __builtin_amdgcn_alignbit(__builtin_bit_cast(int, hi),
                                      __builtin_bit_cast(int, lo), 16);
    return __builtin_bit_cast(h2, r);
}
__device__ __forceinline__ h2 pkrtz(float a, float b) {
    return __builtin_bit_cast(h2, __builtin_amdgcn_cvt_pkrtz(a, b));
}

// Compiler-level memory fence (emits nothing): pins LDS op program order for
// the single-wave read/write discipline on the private data buffer (round-1
// stale-neighbor bug; validated PASS r2/r3/r10/r12-r17).
#define MEMFENCE() asm volatile("" ::: "memory")

// h2 slice k (elements 2k,2k+1) of an h8 — register-select, no instructions
#define SL(W, K) __builtin_shufflevector(W, W, 2*(K), 2*(K)+1)

// one window column at data-dword offset O, taps T..T+2 (weights from LDS,
// r12/r16-proven body): 3 ds_read_b128 + 5 LDS dword data reads +
// 4 alignbit + 12 v_pk_fma_f16 -> all 8 z outputs.
#define COLT(O, T) {                                                           \
    h8 WA = wp8[(T)];                                                          \
    h8 WB = wp8[(T) + 1];                                                      \
    h8 WC = wp8[(T) + 2];                                                      \
    h2 D0 = bp[(O) + 0], D1 = bp[(O) + 1], D2 = bp[(O) + 2],                   \
       D3 = bp[(O) + 3], D4 = bp[(O) + 4];                                     \
    h2 M0 = mid2(D0, D1), M1 = mid2(D1, D2), M2 = mid2(D2, D3),                \
       M3 = mid2(D3, D4);                                                      \
    dd0 = __builtin_elementwise_fma(D0, SL(WA, 0), dd0);                       \
    dd1 = __builtin_elementwise_fma(D1, SL(WA, 1), dd1);                       \
    dd2 = __builtin_elementwise_fma(D2, SL(WA, 2), dd2);                       \
    dd3 = __builtin_elementwise_fma(D3, SL(WA, 3), dd3);                       \
    dd0 = __builtin_elementwise_fma(M0, SL(WB, 0), dd0);                       \
    dd1 = __builtin_elementwise_fma(M1, SL(WB, 1), dd1);                       \
    dd2 = __builtin_elementwise_fma(M2, SL(WB, 2), dd2);                       \
    dd3 = __builtin_elementwise_fma(M3, SL(WB, 3), dd3);                       \
    dd0 = __builtin_elementwise_fma(D1, SL(WC, 0), dd0);                       \
    dd1 = __builtin_elementwise_fma(D2, SL(WC, 1), dd1);                       \
    dd2 = __builtin_elementwise_fma(D3, SL(WC, 2), dd2);                       \
    dd3 = __builtin_elementwise_fma(D4, SL(WC, 3), dd3); }

// own (center) column, taps 12..14: data comes from the loop-carried e0..e4
// REGISTERS (this thread wrote them back last iteration) -> 5 fewer LDS reads
// per iter and 12 FMAs with zero-latency operands.
#define COLT_OWN() {                                                           \
    h8 WA = wp8[12];                                                           \
    h8 WB = wp8[13];                                                           \
    h8 WC = wp8[14];                                                           \
    h2 M0 = mid2(e0, e1), M1 = mid2(e1, e2), M2 = mid2(e2, e3),                \
       M3 = mid2(e3, e4);                                                      \
    dd0 = __builtin_elementwise_fma(e0, SL(WA, 0), dd0);                       \
    dd1 = __builtin_elementwise_fma(e1, SL(WA, 1), dd1);                       \
    dd2 = __builtin_elementwise_fma(e2, SL(WA, 2), dd2);                       \
    dd3 = __builtin_elementwise_fma(e3, SL(WA, 3), dd3);                       \
    dd0 = __builtin_elementwise_fma(M0, SL(WB, 0), dd0);                       \
    dd1 = __builtin_elementwise_fma(M1, SL(WB, 1), dd1);                       \
    dd2 = __builtin_elementwise_fma(M2, SL(WB, 2), dd2);                       \
    dd3 = __builtin_elementwise_fma(M3, SL(WB, 3), dd3);                       \
    dd0 = __builtin_elementwise_fma(e1, SL(WC, 0), dd0);                       \
    dd1 = __builtin_elementwise_fma(e2, SL(WC, 1), dd1);                       \
    dd2 = __builtin_elementwise_fma(e3, SL(WC, 2), dd2);                       \
    dd3 = __builtin_elementwise_fma(e4, SL(WC, 3), dd3); }

// normalized-dot correction + bias + silu + residual for one output
#define OUTK(CK, DDF, SWK, BK, RK) {                                           \
    float u = fmaf(fmaf(SWK, nmean, DDF), istd, BK);                           \
    CK += RK * (u * __builtin_amdgcn_rcpf(1.f + __expf(-u))); }

// r16 structure (best measured: 75.0 us): 8 waves = 8 batches of ONE tile per
// wg, weights staged once per wg into shared LDS, barrier-free per-wave loop.
__global__ __launch_bounds__(512, 1)
void gridnet_kernel(const float* __restrict__ W,
                    const float* __restrict__ Bias,
                    const float* __restrict__ Rs,
                    const float* __restrict__ X,
                    float* __restrict__ Y,
                    int n_batch)
{
    __shared__ __align__(16) int wlds[64 * WSTRIDE];    // 27.6 KB, shared
    __shared__ __align__(16) h2 dbuf[8][500];           // 8 x 2 KB, per-wave

    const int tid  = threadIdx.x;      // 512 threads = 8 waves
    const int wave = tid >> 6;
    const int lane = tid & 63;
    const int lx   = lane >> 3;        // 0..7
    const int ly   = lane & 7;

    // wg = one tile x 8 batches; wave = batch-in-octet
    const int no    = n_batch >> 3;             // batch octets per tile (2)
    const int bid   = (int)blockIdx.x;
    const int r     = bid / no;                 // spatial block 0..511
    const int ob    = bid - r * no;
    const int batch = 8 * ob + wave;
    const int gm0 = (r >> 6) << 3;
    const int gn0 = ((r >> 3) & 7) << 3;
    const int gk0 = (r & 7) << 3;

    const float* xb = X + ((size_t)batch << 18);
    h2* const my = dbuf[wave];

    // -------- data staging (per wave, own batch); stats on rounded ----------
    float s_all = 0.f, q_all = 0.f, s_int = 0.f, q_int = 0.f;
    #pragma unroll 1
    for (int c = lane; c < 100; c += 64) {
        int x = c / 10, y = c - (c / 10) * 10;   // padded coords 0..9
        int m = gm0 + x - 1, n = gn0 + y - 1;
        bool row_ok = ((unsigned)m < 64u) & ((unsigned)n < 64u);
        float4 fa = {0.f, 0.f, 0.f, 0.f}, fb = {0.f, 0.f, 0.f, 0.f};
        float vz0 = 0.f, vz9 = 0.f;
        if (row_ok) {
            const float* rp = xb + (m * 4096 + n * 64);
            fa = *(const float4*)(rp + gk0);          // z = 1..4
            fb = *(const float4*)(rp + gk0 + 4);      // z = 5..8
            if (gk0 > 0)  vz0 = rp[gk0 - 1];          // uniform branches
            if (gk0 < 56) vz9 = rp[gk0 + 8];
        }
        h2 d0 = pkrtz(vz0, fa.x), d1 = pkrtz(fa.y, fa.z), d2 = pkrtz(fa.w, fb.x),
           d3 = pkrtz(fb.y, fb.z), d4 = pkrtz(fb.w, vz9);
        my[c * 5 + 0] = d0; my[c * 5 + 1] = d1; my[c * 5 + 2] = d2;
        my[c * 5 + 3] = d3; my[c * 5 + 4] = d4;
        float t0 = (float)d0.x, t1 = (float)d0.y, t2 = (float)d1.x,
              t3 = (float)d1.y, t4 = (float)d2.x, t5 = (float)d2.y,
              t6 = (float)d3.x, t7 = (float)d3.y, t8 = (float)d4.x,
              t9 = (float)d4.y;
        float s8 = t1 + t2 + t3 + t4 + t5 + t6 + t7 + t8;
        float q8 = t1*t1 + t2*t2 + t3*t3 + t4*t4 + t5*t5 + t6*t6 + t7*t7 + t8*t8;
        s_all += s8 + t0 + t9;
        q_all += q8 + t0*t0 + t9*t9;
        bool inter = ((unsigned)(x - 1) < 8u) & ((unsigned)(y - 1) < 8u);
        if (inter) { s_int += s8; q_int += q8; }
    }

    // -------- cooperative weight staging: 27 taps x 64 positions, once ------
    #pragma unroll 1
    for (int j = tid; j < 1728; j += 512) {
        int tap = j >> 6;                   // 0..26
        int pos = j & 63;
        int plx = pos >> 3, ply = pos & 7;
        const float* wp = W + ((size_t)tap << 18)
                        + (((size_t)(gm0 + plx)) << 12) + ((gn0 + ply) << 6) + gk0;
        float4 fa = *(const float4*)(wp);
        float4 fb = *(const float4*)(wp + 4);
        int4 v = { __builtin_bit_cast(int, pkrtz(fa.x, fa.y)),
                   __builtin_bit_cast(int, pkrtz(fa.z, fa.w)),
                   __builtin_bit_cast(int, pkrtz(fb.x, fb.y)),
                   __builtin_bit_cast(int, pkrtz(fb.z, fb.w)) };
        *(int4*)&wlds[pos * WSTRIDE + tap * 4] = v;     // aligned ds_write_b128
    }

    // -------- per-wave block stats: DPP + readlane only ---------------------
    float S_all = bcast63(wave_sum(s_all));
    float Q_all = bcast63(wave_sum(q_all));
    float Si    = bcast63(wave_sum(s_int));
    float Qi    = bcast63(wave_sum(q_int));
    const float halo_s = S_all - Si;
    const float halo_q = Q_all - Qi;

    __syncthreads();   // the ONLY barrier: weights visible to all 8 waves

    // -------- per-thread loop-invariant state -------------------------------
    const h8* const wp8 = (const h8*)&wlds[lane * WSTRIDE];
    h2* const bp = &my[5 * (lx * 10 + ly)];   // window corner; own col = +55

    // sw sums over the ROUNDED weights (what the dot sees)
    float sw0=0.f, sw1=0.f, sw2=0.f, sw3=0.f, sw4=0.f, sw5=0.f, sw6=0.f, sw7=0.f;
    #pragma unroll
    for (int t = 0; t < 27; ++t) {
        h8 w = wp8[t];
        sw0 += (float)w[0]; sw1 += (float)w[1]; sw2 += (float)w[2];
        sw3 += (float)w[3]; sw4 += (float)w[4]; sw5 += (float)w[5];
        sw6 += (float)w[6]; sw7 += (float)w[7];
    }

    const size_t ofs = (((size_t)(gm0 + lx)) << 12) + ((gn0 + ly) << 6) + gk0;
    float4 ba = *(const float4*)(Bias + ofs), bb = *(const float4*)(Bias + ofs + 4);
    float4 ra = *(const float4*)(Rs + ofs),   rb = *(const float4*)(Rs + ofs + 4);

    // own column state lives in REGISTERS e0..e4 across iterations
    h2 e0 = bp[55], e1 = bp[56], e2 = bp[57], e3 = bp[58], e4 = bp[59];
    float z0f = (float)e0.x, z9f = (float)e4.y;       // frozen z-halo halves
    float c1 = (float)e0.y, c2 = (float)e1.x, c3 = (float)e1.y, c4 = (float)e2.x,
          c5 = (float)e2.y, c6 = (float)e3.x, c7 = (float)e3.y, c8 = (float)e4.x;

    const float inv_n = 1.0f / 1000.0f;

    // 8 iterations, ZERO barriers. unroll 2: lets the scheduler overlap iter
    // i's epilogue/DPP VALU with issuing iter i+1's LDS reads (fences pin only
    // memory order, which stays correct).
    #pragma unroll 2
    for (int it = 0; it < 8; ++it) {
        float mean  = (halo_s + Si) * inv_n;
        float qmean = (halo_q + Qi) * inv_n;
        float istd  = rsqrtf(qmean - mean * mean + 1e-5f);
        float nmean = -mean;

        h2 dd0 = { (_Float16)0.f, (_Float16)0.f };
        h2 dd1 = dd0, dd2 = dd0, dd3 = dd0;
        COLT(0,    0)
        COLT(5,    3)
        COLT(10,   6)
        COLT(50,   9)
        COLT_OWN()
        COLT(60,  15)
        COLT(100, 18)
        COLT(105, 21)
        COLT(110, 24)

        MEMFENCE();  // all column reads issue before the stores below

        OUTK(c1, (float)dd0.x, sw0, ba.x, ra.x)
        OUTK(c2, (float)dd0.y, sw1, ba.y, ra.y)
        OUTK(c3, (float)dd1.x, sw2, ba.z, ra.z)
        OUTK(c4, (float)dd1.y, sw3, ba.w, ra.w)
        OUTK(c5, (float)dd2.x, sw4, bb.x, rb.x)
        OUTK(c6, (float)dd2.y, sw5, bb.y, rb.y)
        OUTK(c7, (float)dd3.x, sw6, bb.z, rb.z)
        OUTK(c8, (float)dd3.y, sw7, bb.w, rb.w)

        if (it != 7) {   // last iteration: no writeback, no stats
            e0 = pkrtz(z0f, c1); e1 = pkrtz(c2, c3); e2 = pkrtz(c4, c5);
            e3 = pkrtz(c6, c7); e4 = pkrtz(c8, z9f);
            bp[55] = e0; bp[56] = e1; bp[57] = e2; bp[58] = e3; bp[59] = e4;

            MEMFENCE();  // stores stay above next iteration's reads

            float sp = ((c1 + c2) + (c3 + c4)) + ((c5 + c6) + (c7 + c8));
            float qp = ((c1*c1 + c2*c2) + (c3*c3 + c4*c4)) +
                       ((c5*c5 + c6*c6) + (c7*c7 + c8*c8));
            Si = bcast63(wave_sum(sp));
            Qi = bcast63(wave_sum(qp));
        }
    }

    float* yp = Y + ((size_t)batch << 18) + ofs;
    *(float4*)(yp)     = make_float4(c1, c2, c3, c4);
    *(float4*)(yp + 4) = make_float4(c5, c6, c7, c8);
}

extern "C" void kernel_launch(void* const* d_in, const int* in_sizes, int n_in,
                              void* d_out, int out_size, void* d_ws, size_t ws_size,
                              hipStream_t stream) {
    const float* W = (const float*)d_in[0];   // (27,64,64,64)
    const float* B = (const float*)d_in[1];   // (64,64,64)
    const float* R = (const float*)d_in[2];   // (64,64,64)
    const float* X = (const float*)d_in[3];   // (16,64,64,64)
    float* Y = (float*)d_out;

    int n_batch = in_sizes[3] >> 18;          // 64^3 per sample (16, div by 8)
    dim3 grid(512 * (n_batch >> 3)), block(512);
    hipLaunchKernelGGL(gridnet_kernel, grid, block, 0, stream, W, B, R, X, Y, n_batch);
}